// Round 1
// baseline (340.524 us; speedup 1.0000x reference)
//
#include <hip/hip_runtime.h>

#define D 128
#define NSEG 4096
#define EPS 1e-5f

__global__ __launch_bounds__(256) void inorm_seg_kernel(
    const float* __restrict__ x,
    const int* __restrict__ batch,
    const float* __restrict__ weight,
    const float* __restrict__ bias,
    float* __restrict__ out,
    int N)
{
    const int g = blockIdx.x;

    // Binary search segment bounds in sorted batch (all threads redundantly).
    int lo = 0, hi = N;
    while (lo < hi) { int mid = (lo + hi) >> 1; if (batch[mid] < g) lo = mid + 1; else hi = mid; }
    const int start = lo;
    hi = N;
    while (lo < hi) { int mid = (lo + hi) >> 1; if (batch[mid] < g + 1) lo = mid + 1; else hi = mid; }
    const int end = lo;
    const int cnt = end - start;
    if (cnt == 0) return;

    const int tid = threadIdx.x;
    const int rq  = tid >> 5;        // row group 0..7
    const int cg  = tid & 31;        // column group: cols [cg*4, cg*4+4)
    const int c0  = cg * 4;

    // ---- Pass 1: accumulate sum and sum-of-squares ----
    float4 s = make_float4(0.f, 0.f, 0.f, 0.f);
    float4 q = make_float4(0.f, 0.f, 0.f, 0.f);
    for (int r = start + rq; r < end; r += 8) {
        const float4 v = *(const float4*)(x + (size_t)r * D + c0);
        s.x += v.x; s.y += v.y; s.z += v.z; s.w += v.w;
        q.x += v.x * v.x; q.y += v.y * v.y; q.z += v.z * v.z; q.w += v.w * v.w;
    }

    __shared__ float s_sum[8][D];
    __shared__ float s_sq[8][D];
    *(float4*)&s_sum[rq][c0] = s;
    *(float4*)&s_sq[rq][c0]  = q;
    __syncthreads();

    __shared__ float s_mean[D];
    __shared__ float s_inv[D];
    if (tid < D) {
        float sum = 0.f, sq = 0.f;
        #pragma unroll
        for (int i = 0; i < 8; ++i) { sum += s_sum[i][tid]; sq += s_sq[i][tid]; }
        const float c    = (float)cnt;       // cnt >= 1 here
        const float mean = sum / c;
        float var = sq / c - mean * mean;
        var = fmaxf(var, 0.f);
        s_mean[tid] = mean;
        s_inv[tid]  = rsqrtf(var + EPS);
    }
    __syncthreads();

    // ---- Pass 2: normalize ----
    const float4 m4 = *(const float4*)&s_mean[c0];
    const float4 i4 = *(const float4*)&s_inv[c0];
    const float4 w4 = *(const float4*)(weight + c0);
    const float4 b4 = *(const float4*)(bias + c0);

    for (int r = start + rq; r < end; r += 8) {
        const size_t off = (size_t)r * D + c0;
        const float4 v = *(const float4*)(x + off);
        float4 o;
        o.x = (v.x - m4.x) * i4.x * w4.x + b4.x;
        o.y = (v.y - m4.y) * i4.y * w4.y + b4.y;
        o.z = (v.z - m4.z) * i4.z * w4.z + b4.z;
        o.w = (v.w - m4.w) * i4.w * w4.w + b4.w;
        *(float4*)(out + off) = o;
    }
}

extern "C" void kernel_launch(void* const* d_in, const int* in_sizes, int n_in,
                              void* d_out, int out_size, void* d_ws, size_t ws_size,
                              hipStream_t stream) {
    const float* x      = (const float*)d_in[0];
    const int*   batch  = (const int*)d_in[1];
    const float* weight = (const float*)d_in[2];
    const float* bias   = (const float*)d_in[3];
    float*       out    = (float*)d_out;
    const int N = in_sizes[0] / D;

    inorm_seg_kernel<<<NSEG, 256, 0, stream>>>(x, batch, weight, bias, out, N);
}

// Round 3
// 238.396 us; speedup vs baseline: 1.4284x; 1.4284x over previous
//
#include <hip/hip_runtime.h>

#define D 128
#define NSEG 4096
#define EPS 1e-5f

typedef float f32x4 __attribute__((ext_vector_type(4)));

__global__ __launch_bounds__(256) void inorm_seg_kernel(
    const float* __restrict__ x,
    const int* __restrict__ batch,
    const float* __restrict__ weight,
    const float* __restrict__ bias,
    float* __restrict__ out,
    int N)
{
    const int g = blockIdx.x;

    // Binary search segment bounds in sorted batch (all threads redundantly;
    // all lanes hit the same address -> broadcast transactions).
    int lo = 0, hi = N;
    while (lo < hi) { int mid = (lo + hi) >> 1; if (batch[mid] < g) lo = mid + 1; else hi = mid; }
    const int start = lo;
    hi = N;
    while (lo < hi) { int mid = (lo + hi) >> 1; if (batch[mid] < g + 1) lo = mid + 1; else hi = mid; }
    const int end = lo;
    const int cnt = end - start;
    if (cnt == 0) return;

    const int tid = threadIdx.x;
    const int rq  = tid >> 5;        // row group 0..7
    const int cg  = tid & 31;        // column group: cols [cg*4, cg*4+4)
    const int c0  = cg * 4;

    // ---- Pass 1: accumulate sum and sum-of-squares, 4x unrolled for MLP ----
    f32x4 s = (f32x4)(0.f);
    f32x4 q = (f32x4)(0.f);

    int r = start + rq;
    for (; r + 24 < end; r += 32) {
        const f32x4 v0 = *(const f32x4*)(x + (size_t)(r     ) * D + c0);
        const f32x4 v1 = *(const f32x4*)(x + (size_t)(r +  8) * D + c0);
        const f32x4 v2 = *(const f32x4*)(x + (size_t)(r + 16) * D + c0);
        const f32x4 v3 = *(const f32x4*)(x + (size_t)(r + 24) * D + c0);
        s += v0; q += v0 * v0;
        s += v1; q += v1 * v1;
        s += v2; q += v2 * v2;
        s += v3; q += v3 * v3;
    }
    for (; r < end; r += 8) {
        const f32x4 v = *(const f32x4*)(x + (size_t)r * D + c0);
        s += v; q += v * v;
    }

    __shared__ float s_sum[8][D];
    __shared__ float s_sq[8][D];
    *(f32x4*)&s_sum[rq][c0] = s;
    *(f32x4*)&s_sq[rq][c0]  = q;
    __syncthreads();

    __shared__ float s_mean[D];
    __shared__ float s_inv[D];
    if (tid < D) {
        float sum = 0.f, sq = 0.f;
        #pragma unroll
        for (int i = 0; i < 8; ++i) { sum += s_sum[i][tid]; sq += s_sq[i][tid]; }
        const float c    = (float)cnt;       // cnt >= 1 here
        const float mean = sum / c;
        float var = sq / c - mean * mean;
        var = fmaxf(var, 0.f);
        s_mean[tid] = mean;
        s_inv[tid]  = rsqrtf(var + EPS);
    }
    __syncthreads();

    // ---- Pass 2: normalize, 4x unrolled; x re-reads hit L2/L3 ----
    const f32x4 m4 = *(const f32x4*)&s_mean[c0];
    const f32x4 i4 = *(const f32x4*)&s_inv[c0];
    const f32x4 w4 = *(const f32x4*)(weight + c0);
    const f32x4 b4 = *(const f32x4*)(bias + c0);

    r = start + rq;
    for (; r + 24 < end; r += 32) {
        const size_t o0 = (size_t)(r     ) * D + c0;
        const size_t o1 = (size_t)(r +  8) * D + c0;
        const size_t o2 = (size_t)(r + 16) * D + c0;
        const size_t o3 = (size_t)(r + 24) * D + c0;
        const f32x4 v0 = *(const f32x4*)(x + o0);
        const f32x4 v1 = *(const f32x4*)(x + o1);
        const f32x4 v2 = *(const f32x4*)(x + o2);
        const f32x4 v3 = *(const f32x4*)(x + o3);
        const f32x4 y0 = (v0 - m4) * i4 * w4 + b4;
        const f32x4 y1 = (v1 - m4) * i4 * w4 + b4;
        const f32x4 y2 = (v2 - m4) * i4 * w4 + b4;
        const f32x4 y3 = (v3 - m4) * i4 * w4 + b4;
        __builtin_nontemporal_store(y0, (f32x4*)(out + o0));
        __builtin_nontemporal_store(y1, (f32x4*)(out + o1));
        __builtin_nontemporal_store(y2, (f32x4*)(out + o2));
        __builtin_nontemporal_store(y3, (f32x4*)(out + o3));
    }
    for (; r < end; r += 8) {
        const size_t o0 = (size_t)r * D + c0;
        const f32x4 v = *(const f32x4*)(x + o0);
        const f32x4 y = (v - m4) * i4 * w4 + b4;
        __builtin_nontemporal_store(y, (f32x4*)(out + o0));
    }
}

extern "C" void kernel_launch(void* const* d_in, const int* in_sizes, int n_in,
                              void* d_out, int out_size, void* d_ws, size_t ws_size,
                              hipStream_t stream) {
    const float* x      = (const float*)d_in[0];
    const int*   batch  = (const int*)d_in[1];
    const float* weight = (const float*)d_in[2];
    const float* bias   = (const float*)d_in[3];
    float*       out    = (float*)d_out;
    const int N = in_sizes[0] / D;

    inorm_seg_kernel<<<NSEG, 256, 0, stream>>>(x, batch, weight, bias, out, N);
}